// Round 6
// baseline (241.351 us; speedup 1.0000x reference)
//
#include <hip/hip_runtime.h>
#include <hip/hip_bf16.h>

// Problem constants
#define BB 8192
#define NN 8192
#define DD 256
#define GAMMA_INV_2SQ 0.0078125f        // 1/(2*8^2) = 1/128
#define EPS_C 0.001f
#define PRE_SCALE (-1.44269504f / 128.f) // -log2e/128 (folded into rsq/xsq)
#define S_COEF    (1.44269504f / 64.f)   //  log2e/64  (coef of S in exp2 arg)

typedef __attribute__((ext_vector_type(4))) float v4f;   // MFMA acc

// ---- fp8 (OCP e4m3) pack: 4 floats -> u32 (byte0=a .. byte3=d)
__device__ __forceinline__ unsigned f2fp8pk4(float a, float b, float c, float d) {
    int v = 0;
    v = __builtin_amdgcn_cvt_pk_fp8_f32(a, b, v, false);
    v = __builtin_amdgcn_cvt_pk_fp8_f32(c, d, v, true);
    return (unsigned)v;
}

// ---- async global->LDS, 16B per lane (lds base wave-uniform)
typedef const __attribute__((address_space(1))) void* gas_t;
typedef __attribute__((address_space(3))) void* las_t;
__device__ __forceinline__ void ld16(const void* g, void* l) {
    __builtin_amdgcn_global_load_lds((gas_t)g, (las_t)l, 16, 0, 0);
}

// ---------------- fused prep (512 blocks x 256):
// blocks [0,256): ref -> swizzled fp8 tile images + rsq_pre (scaled)
// blocks [256,512): x -> fp8 rows + xsq_pre (scaled); block 256 zeroes counters;
//                   zeroM!=0 -> also zero M (atomic fallback path)
__global__ __launch_bounds__(256) void prep_all(const float* __restrict__ ref,
                                                const float* __restrict__ x,
                                                unsigned char* __restrict__ sAg,
                                                unsigned char* __restrict__ sTg,
                                                unsigned char* __restrict__ sT2g,
                                                unsigned char* __restrict__ xbf8,
                                                float* __restrict__ rsq_pre,
                                                float* __restrict__ xsq_pre,
                                                unsigned* __restrict__ cnt,
                                                float* __restrict__ M,
                                                int zeroM) {
    __shared__ float tile[32][257];
    __shared__ float rs[32];
    const int tid = threadIdx.x;
    if (blockIdx.x < 256) {
        const int n0 = blockIdx.x * 32;
        if (tid < 32) rs[tid] = 0.f;
        __syncthreads();
        const int r = tid >> 3, p8 = tid & 7;
        float partial = 0.f;
#pragma unroll
        for (int j = 0; j < 8; ++j) {
            const int c = p8 * 32 + j * 4;
            const float4 v = *(const float4*)(ref + (size_t)(n0 + r) * DD + c);
            partial += v.x * v.x + v.y * v.y + v.z * v.z + v.w * v.w;
            tile[r][c + 0] = v.x; tile[r][c + 1] = v.y;
            tile[r][c + 2] = v.z; tile[r][c + 3] = v.w;
        }
        atomicAdd(&rs[r], partial);
        __syncthreads();
        if (tid < 32) rsq_pre[n0 + tid] = rs[tid] * PRE_SCALE;
        // sAg image: byte[r*256 + cp*8 + j], cp=(c&16)|((c^(r&15))&15)
        {
            unsigned char* dstA = sAg + (size_t)blockIdx.x * 8192 + r * 256;
#pragma unroll
            for (int c4 = 0; c4 < 4; ++c4) {
                const int c = p8 * 4 + c4;
                const float* s = &tile[r][c * 8];
                const unsigned lo = f2fp8pk4(s[0], s[1], s[2], s[3]);
                const unsigned hi = f2fp8pk4(s[4], s[5], s[6], s[7]);
                const int cp = (c & 16) | ((c ^ (r & 15)) & 15);
                *(uint2*)(dstA + cp * 8) = make_uint2(lo, hi);
            }
        }
        // sTg/sT2g: byte[d*32 + cp*8 + j], cp=c^((d>>2)&3); thread owns column d=tid
        {
            const int d = tid;
            uint2 ch1[4], ch2[4];
#pragma unroll
            for (int c = 0; c < 4; ++c) {
                float v[8], v2[8];
#pragma unroll
                for (int j = 0; j < 8; ++j) { v[j] = tile[c * 8 + j][d]; v2[j] = v[j] * v[j]; }
                const int cp = c ^ ((d >> 2) & 3);
                ch1[cp] = make_uint2(f2fp8pk4(v[0], v[1], v[2], v[3]), f2fp8pk4(v[4], v[5], v[6], v[7]));
                ch2[cp] = make_uint2(f2fp8pk4(v2[0], v2[1], v2[2], v2[3]), f2fp8pk4(v2[4], v2[5], v2[6], v2[7]));
            }
            unsigned char* dT  = sTg  + (size_t)blockIdx.x * 8192 + d * 32;
            unsigned char* dT2 = sT2g + (size_t)blockIdx.x * 8192 + d * 32;
            *(uint4*)(dT)       = make_uint4(ch1[0].x, ch1[0].y, ch1[1].x, ch1[1].y);
            *(uint4*)(dT + 16)  = make_uint4(ch1[2].x, ch1[2].y, ch1[3].x, ch1[3].y);
            *(uint4*)(dT2)      = make_uint4(ch2[0].x, ch2[0].y, ch2[1].x, ch2[1].y);
            *(uint4*)(dT2 + 16) = make_uint4(ch2[2].x, ch2[2].y, ch2[3].x, ch2[3].y);
        }
    } else {
        const int blk = blockIdx.x - 256;
        const int b0 = blk * 32;
        if (blk == 0 && tid < 128) cnt[tid] = 0u;
        if (tid < 32) rs[tid] = 0.f;
        __syncthreads();
        const int r = tid >> 3, p8 = tid & 7;
        float partial = 0.f;
        unsigned pk[8];
#pragma unroll
        for (int j = 0; j < 8; ++j) {
            const int c = p8 * 32 + j * 4;
            const float4 v = *(const float4*)(x + (size_t)(b0 + r) * DD + c);
            partial += v.x * v.x + v.y * v.y + v.z * v.z + v.w * v.w;
            pk[j] = f2fp8pk4(v.x, v.y, v.z, v.w);
        }
        atomicAdd(&rs[r], partial);
        unsigned char* dst = xbf8 + (size_t)(b0 + r) * DD + p8 * 32;
        *(uint4*)(dst)      = make_uint4(pk[0], pk[1], pk[2], pk[3]);
        *(uint4*)(dst + 16) = make_uint4(pk[4], pk[5], pk[6], pk[7]);
        __syncthreads();
        if (tid < 32) xsq_pre[b0 + tid] = rs[tid] * PRE_SCALE;
        if (zeroM) {
            float4* mz = (float4*)M + (size_t)blk * 2048;
#pragma unroll
            for (int j = 0; j < 8; ++j)
                mz[j * 256 + tid] = make_float4(0.f, 0.f, 0.f, 0.f);
        }
    }
}

// ---------------- main fused kernel: fp8 MFMA, 1 barrier/iter, async staging,
// fused last-block finish (partials path). grid = 512 blocks, 512 threads.
// LDS: sA 2x8K | sT 3x8K | sT2 3x8K | sW 2x2K | rsq 8K | wsum 512B
#define SA_OFF   0
#define ST_OFF   16384
#define ST2_OFF  40960
#define SW_OFF   65536
#define SRSQ_OFF 69632
#define SWS_OFF  77824
#define SMEM_SZ  78336

template <bool ATOMIC>
__global__ __launch_bounds__(512, 4) void hland_main(
        const unsigned char* __restrict__ sAg,
        const unsigned char* __restrict__ sTg,
        const unsigned char* __restrict__ sT2g,
        const float* __restrict__ rsq_pre,
        const float* __restrict__ xsq_pre,
        const unsigned char* __restrict__ xbf8,
        const float* __restrict__ x_t,
        const float* __restrict__ Wp,
        unsigned* __restrict__ cnt,
        float* __restrict__ M,          // ATOMIC: final M accum; else 4 partials
        float* __restrict__ out) {      // partials path: final output
    __shared__ __align__(16) char smem[SMEM_SZ];

    const int tid = threadIdx.x;
    const int wave = tid >> 6, lane = tid & 63;
    const int quad = lane >> 4, l16 = lane & 15;
    // XCD swizzle: blocks on XCD j (= blk%8) share n-quarter q=j>>1
    const int q = (blockIdx.x & 7) >> 1;
    const int btile = ((blockIdx.x >> 3) << 1) | (blockIdx.x & 1);
    const int b0 = btile * 64;
    const int tn0 = q * 64;
    const int nt = wave & 1, btA = wave >> 1, dq = wave;

    const float xsqp_lane = xsq_pre[b0 + btA * 16 + l16];
    float wsum_acc = 0.f;
    v4f acc2[4][2], acc1[4][2];
#pragma unroll
    for (int i = 0; i < 4; ++i)
#pragma unroll
        for (int j = 0; j < 2; ++j) { acc2[i][j] = (v4f){0,0,0,0}; acc1[i][j] = (v4f){0,0,0,0}; }

    // hoisted loop-invariant x fragments (B operand of Phase B)
    long bfr[8];
    {
        const unsigned char* xb = xbf8 + (size_t)(b0 + btA * 16 + l16) * 256 + quad * 8;
#pragma unroll
        for (int kc = 0; kc < 8; ++kc) bfr[kc] = *(const long*)(xb + kc * 32);
    }

    const int stage_goff = wave * 1024 + lane * 16;
    const int stage_loff = wave * 1024;

    // prologue: stage rsq_pre quarter (8 KB) + tile 0
    ((float4*)(smem + SRSQ_OFF))[tid] = ((const float4*)(rsq_pre + tn0 * 32))[tid];
    {
        const size_t g = (size_t)tn0 * 8192 + stage_goff;
        ld16(sAg + g,  smem + SA_OFF  + stage_loff);
        ld16(sTg + g,  smem + ST_OFF  + stage_loff);
        ld16(sT2g + g, smem + ST2_OFF + stage_loff);
    }
    __syncthreads();

    int sp = 0, tp = 0;
    for (int it = 0; it < 64; ++it) {
        const int spn = sp ^ 1;
        const int tpn = (tp == 2) ? 0 : tp + 1;
        const int tpd = (tp == 0) ? 2 : tp - 1;

        if (it < 63) {
            const size_t g = (size_t)(tn0 + it + 1) * 8192 + stage_goff;
            ld16(sAg + g,  smem + SA_OFF  + spn * 8192 + stage_loff);
            ld16(sTg + g,  smem + ST_OFF  + tpn * 8192 + stage_loff);
            ld16(sT2g + g, smem + ST2_OFF + tpn * 8192 + stage_loff);
        }

        // ---- Phase B(it): S^T[n][b], two independent MFMA chains
        v4f S0 = (v4f){0,0,0,0}, S1 = (v4f){0,0,0,0};
        {
            const char* saB = smem + SA_OFF + sp * 8192 + (nt * 16 + l16) * 256;
#pragma unroll
            for (int kp = 0; kp < 4; ++kp) {
                const int c0 = (2 * kp) * 4 + quad;
                const int c1 = (2 * kp + 1) * 4 + quad;
                const int cp0 = (c0 & 16) | ((c0 ^ l16) & 15);
                const int cp1 = (c1 & 16) | ((c1 ^ l16) & 15);
                const long a0 = *(const long*)(saB + cp0 * 8);
                const long a1 = *(const long*)(saB + cp1 * 8);
                S0 = __builtin_amdgcn_mfma_f32_16x16x32_fp8_fp8(a0, bfr[2 * kp], S0, 0, 0, 0);
                S1 = __builtin_amdgcn_mfma_f32_16x16x32_fp8_fp8(a1, bfr[2 * kp + 1], S1, 0, 0, 0);
            }
        }
        const v4f S = S0 + S1;

        // ---- Phase C(it): w = exp2(pre + S*coef); write 64*w fp8 to sW[sp]
        {
            const float4 r4 = *(const float4*)(smem + SRSQ_OFF + it * 128 + nt * 64 + quad * 16);
            float w4[4];
            w4[0] = exp2f(fmaf(S[0], S_COEF, xsqp_lane + r4.x));
            w4[1] = exp2f(fmaf(S[1], S_COEF, xsqp_lane + r4.y));
            w4[2] = exp2f(fmaf(S[2], S_COEF, xsqp_lane + r4.z));
            w4[3] = exp2f(fmaf(S[3], S_COEF, xsqp_lane + r4.w));
            wsum_acc += w4[0] + w4[1] + w4[2] + w4[3];
            const unsigned pk = f2fp8pk4(w4[0] * 64.f, w4[1] * 64.f, w4[2] * 64.f, w4[3] * 64.f);
            const int bl = btA * 16 + l16;
            const int c8 = nt * 2 + (quad >> 1);
            *(unsigned*)(smem + SW_OFF + sp * 2048 + bl * 32
                         + (c8 ^ ((bl >> 2) & 3)) * 8 + (quad & 1) * 4) = pk;
        }

        // ---- Phase D(it-1)
        if (it > 0) {
            const char* swb  = smem + SW_OFF  + spn * 2048;
            const char* stb  = smem + ST_OFF  + tpd * 8192;
            const char* st2b = smem + ST2_OFF + tpd * 8192;
            long wf[4];
#pragma unroll
            for (int bt = 0; bt < 4; ++bt) {
                const int bl = bt * 16 + l16;
                wf[bt] = *(const long*)(swb + bl * 32 + (quad ^ ((bl >> 2) & 3)) * 8);
            }
#pragma unroll
            for (int dt = 0; dt < 2; ++dt) {
                const int d = dq * 32 + dt * 16 + l16;
                const int co = (quad ^ ((d >> 2) & 3)) * 8;
                const long bT  = *(const long*)(stb  + d * 32 + co);
                const long bT2 = *(const long*)(st2b + d * 32 + co);
#pragma unroll
                for (int bt = 0; bt < 4; ++bt) {
                    acc2[bt][dt] = __builtin_amdgcn_mfma_f32_16x16x32_fp8_fp8(wf[bt], bT2, acc2[bt][dt], 0, 0, 0);
                    acc1[bt][dt] = __builtin_amdgcn_mfma_f32_16x16x32_fp8_fp8(wf[bt], bT,  acc1[bt][dt], 0, 0, 0);
                }
            }
        }
        __syncthreads();
        sp = spn; tp = tpn;
    }

    // ---- final Phase D(63)
    {
        const int tpd = (tp == 0) ? 2 : tp - 1;
        const int wsl = sp ^ 1;
        const char* swb  = smem + SW_OFF  + wsl * 2048;
        const char* stb  = smem + ST_OFF  + tpd * 8192;
        const char* st2b = smem + ST2_OFF + tpd * 8192;
        long wf[4];
#pragma unroll
        for (int bt = 0; bt < 4; ++bt) {
            const int bl = bt * 16 + l16;
            wf[bt] = *(const long*)(swb + bl * 32 + (quad ^ ((bl >> 2) & 3)) * 8);
        }
#pragma unroll
        for (int dt = 0; dt < 2; ++dt) {
            const int d = dq * 32 + dt * 16 + l16;
            const int co = (quad ^ ((d >> 2) & 3)) * 8;
            const long bT  = *(const long*)(stb  + d * 32 + co);
            const long bT2 = *(const long*)(st2b + d * 32 + co);
#pragma unroll
            for (int bt = 0; bt < 4; ++bt) {
                acc2[bt][dt] = __builtin_amdgcn_mfma_f32_16x16x32_fp8_fp8(wf[bt], bT2, acc2[bt][dt], 0, 0, 0);
                acc1[bt][dt] = __builtin_amdgcn_mfma_f32_16x16x32_fp8_fp8(wf[bt], bT,  acc1[bt][dt], 0, 0, 0);
            }
        }
    }

    // ---- epilogue: wsum reduce, combine M partial, store
    float v = wsum_acc;
    v += __shfl_xor(v, 16, 64);
    v += __shfl_xor(v, 32, 64);
    float* swsum = (float*)(smem + SWS_OFF);
    if (lane < 16) swsum[wave * 16 + lane] = v;
    __syncthreads();

    float* Mq = ATOMIC ? M : (M + (size_t)q * BB * DD);
    const float inv64 = 0.015625f;
    float mreg[4][2][4];
#pragma unroll
    for (int bt = 0; bt < 4; ++bt) {
#pragma unroll
        for (int dt = 0; dt < 2; ++dt) {
            const int d = dq * 32 + dt * 16 + l16;
#pragma unroll
            for (int r = 0; r < 4; ++r) {
                const int bl = bt * 16 + quad * 4 + r;
                const int b = b0 + bl;
                const float wsb = swsum[(bt * 2) * 16 + (quad * 4 + r)]
                                + swsum[(bt * 2 + 1) * 16 + (quad * 4 + r)];
                const float xv = x_t[(size_t)b * DD + d];
                const float m = (acc2[bt][dt][r] - 2.f * xv * acc1[bt][dt][r]) * inv64
                              + xv * xv * wsb;
                mreg[bt][dt][r] = m;
                if (ATOMIC) atomicAdd(&Mq[(size_t)b * DD + d], m);
                else        Mq[(size_t)b * DD + d] = m;
            }
        }
    }

    if (!ATOMIC) {
        // ---- fused finish: last of the 4 q-blocks per btile finalizes out
        __syncthreads();                 // all partial stores complete (barrier drains vmcnt)
        unsigned* flag = (unsigned*)smem;
        if (tid == 0) {
            __threadfence();             // release: flush this XCD's L2 to coherent point
            const unsigned old = atomicAdd(&cnt[btile], 1u);
            *flag = (old == 3u) ? 1u : 0u;
        }
        __syncthreads();
        if (*flag) {
            __threadfence();             // acquire: invalidate stale lines
            const float W0 = Wp[0];
            const float* p0 = M + (size_t)((q + 1) & 3) * (BB * DD);
            const float* p1 = M + (size_t)((q + 2) & 3) * (BB * DD);
            const float* p2 = M + (size_t)((q + 3) & 3) * (BB * DD);
#pragma unroll
            for (int bt = 0; bt < 4; ++bt) {
#pragma unroll
                for (int dt = 0; dt < 2; ++dt) {
                    const int d = dq * 32 + dt * 16 + l16;
#pragma unroll
                    for (int r = 0; r < 4; ++r) {
                        const int bl = bt * 16 + quad * 4 + r;
                        const size_t idx = (size_t)(b0 + bl) * DD + d;
                        const float s = mreg[bt][dt][r] + p0[idx] + p1[idx] + p2[idx];
                        out[idx] = 1.f / (W0 * s + EPS_C);
                    }
                }
            }
        }
    }
}

// ---------------- finish (atomic path): out = 1/(W*M + eps) in place
__global__ __launch_bounds__(256) void finish_k(float* __restrict__ M,
                                                const float* __restrict__ W) {
    const int i = blockIdx.x * blockDim.x + threadIdx.x;
    const float W0 = W[0];
    float4 m = ((const float4*)M)[i];
    float4 o;
    o.x = 1.f / (W0 * m.x + EPS_C);
    o.y = 1.f / (W0 * m.y + EPS_C);
    o.z = 1.f / (W0 * m.z + EPS_C);
    o.w = 1.f / (W0 * m.w + EPS_C);
    ((float4*)M)[i] = o;
}

// ---------------- fallback: fp32, ZERO workspace (safety net)
__global__ __launch_bounds__(256) void hland_fb(const float* __restrict__ x_t,
                                                const float* __restrict__ ref,
                                                float* __restrict__ M) {
    __shared__ float xs[8][257];
    __shared__ float rt[32][257];
    __shared__ float Sv[8][32];
    __shared__ float wv[8][32];
    __shared__ float rsq_s[32];
    __shared__ float xsq_s[8];
    const int t = threadIdx.x;
    const int b0 = blockIdx.x * 8;
    if (t < 8) xsq_s[t] = 0.f;
    __syncthreads();
    {
        const int r = t >> 5, c = (t & 31) * 8;
        const float4 a = *(const float4*)(x_t + (size_t)(b0 + r) * DD + c);
        const float4 b = *(const float4*)(x_t + (size_t)(b0 + r) * DD + c + 4);
        xs[r][c + 0] = a.x; xs[r][c + 1] = a.y; xs[r][c + 2] = a.z; xs[r][c + 3] = a.w;
        xs[r][c + 4] = b.x; xs[r][c + 5] = b.y; xs[r][c + 6] = b.z; xs[r][c + 7] = b.w;
        atomicAdd(&xsq_s[r], a.x*a.x+a.y*a.y+a.z*a.z+a.w*a.w + b.x*b.x+b.y*b.y+b.z*b.z+b.w*b.w);
    }
    __syncthreads();
    float acc2[8], acc1[8], wsum[8];
#pragma unroll
    for (int b = 0; b < 8; ++b) { acc2[b] = 0.f; acc1[b] = 0.f; wsum[b] = 0.f; }
    const int sr = t >> 3, sg = t & 7;
    for (int tile = 0; tile < NN / 32; ++tile) {
        const int n0 = tile * 32;
        Sv[t >> 5][t & 31] = 0.f;
        if (t < 32) rsq_s[t] = 0.f;
        __syncthreads();
        {
            float p = 0.f;
#pragma unroll
            for (int j = 0; j < 8; ++j) {
                const int c = sg * 32 + j * 4;
                const float4 v = *(const float4*)(ref + (size_t)(n0 + sr) * DD + c);
                rt[sr][c + 0] = v.x; rt[sr][c + 1] = v.y; rt[sr][c + 2] = v.z; rt[sr][c + 3] = v.w;
                p += v.x * v.x + v.y * v.y + v.z * v.z + v.w * v.w;
            }
            atomicAdd(&rsq_s[sr], p);
        }
        __syncthreads();
        {
            float part[8];
#pragma unroll
            for (int b = 0; b < 8; ++b) part[b] = 0.f;
            for (int jj = 0; jj < 32; ++jj) {
                const int c = sg * 32 + ((jj + sg * 4) & 31);
                const float rv = rt[sr][c];
#pragma unroll
                for (int b = 0; b < 8; ++b) part[b] += xs[b][c] * rv;
            }
#pragma unroll
            for (int b = 0; b < 8; ++b) atomicAdd(&Sv[b][sr], part[b]);
        }
        __syncthreads();
        {
            const int b = t >> 5, n = t & 31;
            const float dist = xsq_s[b] + rsq_s[n] - 2.f * Sv[b][n];
            wv[b][n] = __expf(dist * (-GAMMA_INV_2SQ));
        }
        __syncthreads();
        for (int n = 0; n < 32; ++n) {
            const float rv = rt[n][t];
            const float rv2 = rv * rv;
#pragma unroll
            for (int b = 0; b < 8; ++b) {
                const float w = wv[b][n];
                acc1[b] += w * rv; acc2[b] += w * rv2; wsum[b] += w;
            }
        }
        __syncthreads();
    }
#pragma unroll
    for (int b = 0; b < 8; ++b) {
        const float xv = xs[b][t];
        M[(size_t)(b0 + b) * DD + t] = acc2[b] - 2.f * xv * acc1[b] + xv * xv * wsum[b];
    }
}

extern "C" void kernel_launch(void* const* d_in, const int* in_sizes, int n_in,
                              void* d_out, int out_size, void* d_ws, size_t ws_size,
                              hipStream_t stream) {
    const float* x_t = (const float*)d_in[0];
    const float* ref = (const float*)d_in[1];
    const float* W   = (const float*)d_in[2];
    float* out = (float*)d_out;

    const size_t PART_SZ = (size_t)BB * DD * 4;                       // 8 MB per partial
    const size_t TILES_SZ = (size_t)8 * 1024 * 1024 + 96 * 1024;      // images + rsq/xsq/cnt
    const size_t WS_A = 4 * PART_SZ + TILES_SZ;                       // ~40.1 MB
    const size_t WS_B = TILES_SZ;                                     // ~8.1 MB

    if (ws_size >= WS_B) {
        const bool partials = (ws_size >= WS_A);
        char* ws = (char*)d_ws;
        float* Mp = (float*)ws;                                       // 4 partials (path A)
        char* tb = partials ? (ws + 4 * PART_SZ) : ws;
        unsigned char* sAg  = (unsigned char*)(tb);
        unsigned char* sTg  = (unsigned char*)(tb + (size_t)2 * 1024 * 1024);
        unsigned char* sT2g = (unsigned char*)(tb + (size_t)4 * 1024 * 1024);
        unsigned char* xbf8 = (unsigned char*)(tb + (size_t)6 * 1024 * 1024);
        float* rsq = (float*)(tb + (size_t)8 * 1024 * 1024);
        float* xsq = (float*)(tb + (size_t)8 * 1024 * 1024 + 32768);
        unsigned* cnt = (unsigned*)(tb + (size_t)8 * 1024 * 1024 + 65536);

        prep_all<<<512, 256, 0, stream>>>(ref, x_t, sAg, sTg, sT2g, xbf8, rsq, xsq,
                                          cnt, out, partials ? 0 : 1);
        if (partials) {
            hland_main<false><<<512, 512, 0, stream>>>(sAg, sTg, sT2g, rsq, xsq, xbf8,
                                                       x_t, W, cnt, Mp, out);
        } else {
            hland_main<true><<<512, 512, 0, stream>>>(sAg, sTg, sT2g, rsq, xsq, xbf8,
                                                      x_t, W, cnt, out, out);
            finish_k<<<(BB * DD / 4) / 256, 256, 0, stream>>>(out, W);
        }
    } else {
        hland_fb<<<BB / 8, 256, 0, stream>>>(x_t, ref, out);
        finish_k<<<(BB * DD / 4) / 256, 256, 0, stream>>>(out, W);
    }
}

// Round 7
// 158.389 us; speedup vs baseline: 1.5238x; 1.5238x over previous
//
#include <hip/hip_runtime.h>
#include <hip/hip_bf16.h>

// Problem constants
#define BB 8192
#define NN 8192
#define DD 256
#define GAMMA_INV_2SQ 0.0078125f        // 1/(2*8^2) = 1/128
#define EPS_C 0.001f
#define PRE_SCALE (-1.44269504f / 128.f) // -log2e/128 (folded into rsq/xsq)
#define S_COEF    (1.44269504f / 64.f)   //  log2e/64  (coef of S in exp2 arg)

typedef __attribute__((ext_vector_type(4))) float v4f;   // MFMA acc

// ---- fp8 (OCP e4m3) pack: 4 floats -> u32 (byte0=a .. byte3=d)
__device__ __forceinline__ unsigned f2fp8pk4(float a, float b, float c, float d) {
    int v = 0;
    v = __builtin_amdgcn_cvt_pk_fp8_f32(a, b, v, false);
    v = __builtin_amdgcn_cvt_pk_fp8_f32(c, d, v, true);
    return (unsigned)v;
}

// ---- async global->LDS, 16B per lane (lds base wave-uniform)
typedef const __attribute__((address_space(1))) void* gas_t;
typedef __attribute__((address_space(3))) void* las_t;
__device__ __forceinline__ void ld16(const void* g, void* l) {
    __builtin_amdgcn_global_load_lds((gas_t)g, (las_t)l, 16, 0, 0);
}

// ---------------- fused prep (512 blocks x 256):
// blocks [0,256): ref -> swizzled fp8 tile images + rsq_pre (scaled)
// blocks [256,512): x -> fp8 rows + xsq_pre (scaled); zeroM -> zero M (atomic path)
__global__ __launch_bounds__(256) void prep_all(const float* __restrict__ ref,
                                                const float* __restrict__ x,
                                                unsigned char* __restrict__ sAg,
                                                unsigned char* __restrict__ sTg,
                                                unsigned char* __restrict__ sT2g,
                                                unsigned char* __restrict__ xbf8,
                                                float* __restrict__ rsq_pre,
                                                float* __restrict__ xsq_pre,
                                                float* __restrict__ M,
                                                int zeroM) {
    __shared__ float tile[32][257];
    __shared__ float rs[32];
    const int tid = threadIdx.x;
    if (blockIdx.x < 256) {
        const int n0 = blockIdx.x * 32;
        if (tid < 32) rs[tid] = 0.f;
        __syncthreads();
        const int r = tid >> 3, p8 = tid & 7;
        float partial = 0.f;
#pragma unroll
        for (int j = 0; j < 8; ++j) {
            const int c = p8 * 32 + j * 4;
            const float4 v = *(const float4*)(ref + (size_t)(n0 + r) * DD + c);
            partial += v.x * v.x + v.y * v.y + v.z * v.z + v.w * v.w;
            tile[r][c + 0] = v.x; tile[r][c + 1] = v.y;
            tile[r][c + 2] = v.z; tile[r][c + 3] = v.w;
        }
        atomicAdd(&rs[r], partial);
        __syncthreads();
        if (tid < 32) rsq_pre[n0 + tid] = rs[tid] * PRE_SCALE;
        // sAg image: byte[r*256 + cp*8 + j], cp=(c&16)|((c^(r&15))&15)
        {
            unsigned char* dstA = sAg + (size_t)blockIdx.x * 8192 + r * 256;
#pragma unroll
            for (int c4 = 0; c4 < 4; ++c4) {
                const int c = p8 * 4 + c4;
                const float* s = &tile[r][c * 8];
                const unsigned lo = f2fp8pk4(s[0], s[1], s[2], s[3]);
                const unsigned hi = f2fp8pk4(s[4], s[5], s[6], s[7]);
                const int cp = (c & 16) | ((c ^ (r & 15)) & 15);
                *(uint2*)(dstA + cp * 8) = make_uint2(lo, hi);
            }
        }
        // sTg/sT2g: byte[d*32 + cp*8 + j], cp=c^((d>>2)&3); thread owns column d=tid
        {
            const int d = tid;
            uint2 ch1[4], ch2[4];
#pragma unroll
            for (int c = 0; c < 4; ++c) {
                float v[8], v2[8];
#pragma unroll
                for (int j = 0; j < 8; ++j) { v[j] = tile[c * 8 + j][d]; v2[j] = v[j] * v[j]; }
                const int cp = c ^ ((d >> 2) & 3);
                ch1[cp] = make_uint2(f2fp8pk4(v[0], v[1], v[2], v[3]), f2fp8pk4(v[4], v[5], v[6], v[7]));
                ch2[cp] = make_uint2(f2fp8pk4(v2[0], v2[1], v2[2], v2[3]), f2fp8pk4(v2[4], v2[5], v2[6], v2[7]));
            }
            unsigned char* dT  = sTg  + (size_t)blockIdx.x * 8192 + d * 32;
            unsigned char* dT2 = sT2g + (size_t)blockIdx.x * 8192 + d * 32;
            *(uint4*)(dT)       = make_uint4(ch1[0].x, ch1[0].y, ch1[1].x, ch1[1].y);
            *(uint4*)(dT + 16)  = make_uint4(ch1[2].x, ch1[2].y, ch1[3].x, ch1[3].y);
            *(uint4*)(dT2)      = make_uint4(ch2[0].x, ch2[0].y, ch2[1].x, ch2[1].y);
            *(uint4*)(dT2 + 16) = make_uint4(ch2[2].x, ch2[2].y, ch2[3].x, ch2[3].y);
        }
    } else {
        const int blk = blockIdx.x - 256;
        const int b0 = blk * 32;
        if (tid < 32) rs[tid] = 0.f;
        __syncthreads();
        const int r = tid >> 3, p8 = tid & 7;
        float partial = 0.f;
        unsigned pk[8];
#pragma unroll
        for (int j = 0; j < 8; ++j) {
            const int c = p8 * 32 + j * 4;
            const float4 v = *(const float4*)(x + (size_t)(b0 + r) * DD + c);
            partial += v.x * v.x + v.y * v.y + v.z * v.z + v.w * v.w;
            pk[j] = f2fp8pk4(v.x, v.y, v.z, v.w);
        }
        atomicAdd(&rs[r], partial);
        unsigned char* dst = xbf8 + (size_t)(b0 + r) * DD + p8 * 32;
        *(uint4*)(dst)      = make_uint4(pk[0], pk[1], pk[2], pk[3]);
        *(uint4*)(dst + 16) = make_uint4(pk[4], pk[5], pk[6], pk[7]);
        __syncthreads();
        if (tid < 32) xsq_pre[b0 + tid] = rs[tid] * PRE_SCALE;
        if (zeroM) {
            float4* mz = (float4*)M + (size_t)blk * 2048;
#pragma unroll
            for (int j = 0; j < 8; ++j)
                mz[j * 256 + tid] = make_float4(0.f, 0.f, 0.f, 0.f);
        }
    }
}

// ---------------- main fused kernel: fp8 MFMA, 1 barrier/iter, async staging
// grid = 512 blocks (XCD-swizzled), 512 threads (8 waves)
// LDS: sA 2x8K | sT 3x8K | sT2 3x8K | sW 2x2K | rsq 8K | wsum 512B
#define SA_OFF   0
#define ST_OFF   16384
#define ST2_OFF  40960
#define SW_OFF   65536
#define SRSQ_OFF 69632
#define SWS_OFF  77824
#define SMEM_SZ  78336

template <bool ATOMIC>
__global__ __launch_bounds__(512, 4) void hland_main(
        const unsigned char* __restrict__ sAg,
        const unsigned char* __restrict__ sTg,
        const unsigned char* __restrict__ sT2g,
        const float* __restrict__ rsq_pre,
        const float* __restrict__ xsq_pre,
        const unsigned char* __restrict__ xbf8,
        const float* __restrict__ x_t,
        float* __restrict__ M) {        // ATOMIC: final M accum; else 4 partials
    __shared__ __align__(16) char smem[SMEM_SZ];

    const int tid = threadIdx.x;
    const int wave = tid >> 6, lane = tid & 63;
    const int quad = lane >> 4, l16 = lane & 15;
    // XCD swizzle: blocks on XCD j (= blk%8) share n-quarter q=j>>1
    const int q = (blockIdx.x & 7) >> 1;
    const int btile = ((blockIdx.x >> 3) << 1) | (blockIdx.x & 1);
    const int b0 = btile * 64;
    const int tn0 = q * 64;
    const int nt = wave & 1, btA = wave >> 1, dq = wave;

    const float xsqp_lane = xsq_pre[b0 + btA * 16 + l16];
    float wsum_acc = 0.f;
    v4f acc2[4][2], acc1[4][2];
#pragma unroll
    for (int i = 0; i < 4; ++i)
#pragma unroll
        for (int j = 0; j < 2; ++j) { acc2[i][j] = (v4f){0,0,0,0}; acc1[i][j] = (v4f){0,0,0,0}; }

    // hoisted loop-invariant x fragments (B operand of Phase B)
    long bfr[8];
    {
        const unsigned char* xb = xbf8 + (size_t)(b0 + btA * 16 + l16) * 256 + quad * 8;
#pragma unroll
        for (int kc = 0; kc < 8; ++kc) bfr[kc] = *(const long*)(xb + kc * 32);
    }

    const int stage_goff = wave * 1024 + lane * 16;
    const int stage_loff = wave * 1024;

    // prologue: stage rsq_pre quarter (8 KB) + tile 0
    ((float4*)(smem + SRSQ_OFF))[tid] = ((const float4*)(rsq_pre + tn0 * 32))[tid];
    {
        const size_t g = (size_t)tn0 * 8192 + stage_goff;
        ld16(sAg + g,  smem + SA_OFF  + stage_loff);
        ld16(sTg + g,  smem + ST_OFF  + stage_loff);
        ld16(sT2g + g, smem + ST2_OFF + stage_loff);
    }
    __syncthreads();

    int sp = 0, tp = 0;
    for (int it = 0; it < 64; ++it) {
        const int spn = sp ^ 1;
        const int tpn = (tp == 2) ? 0 : tp + 1;
        const int tpd = (tp == 0) ? 2 : tp - 1;

        if (it < 63) {
            const size_t g = (size_t)(tn0 + it + 1) * 8192 + stage_goff;
            ld16(sAg + g,  smem + SA_OFF  + spn * 8192 + stage_loff);
            ld16(sTg + g,  smem + ST_OFF  + tpn * 8192 + stage_loff);
            ld16(sT2g + g, smem + ST2_OFF + tpn * 8192 + stage_loff);
        }

        // ---- Phase B(it): S^T[n][b], two independent MFMA chains
        v4f S0 = (v4f){0,0,0,0}, S1 = (v4f){0,0,0,0};
        {
            const char* saB = smem + SA_OFF + sp * 8192 + (nt * 16 + l16) * 256;
#pragma unroll
            for (int kp = 0; kp < 4; ++kp) {
                const int c0 = (2 * kp) * 4 + quad;
                const int c1 = (2 * kp + 1) * 4 + quad;
                const int cp0 = (c0 & 16) | ((c0 ^ l16) & 15);
                const int cp1 = (c1 & 16) | ((c1 ^ l16) & 15);
                const long a0 = *(const long*)(saB + cp0 * 8);
                const long a1 = *(const long*)(saB + cp1 * 8);
                S0 = __builtin_amdgcn_mfma_f32_16x16x32_fp8_fp8(a0, bfr[2 * kp], S0, 0, 0, 0);
                S1 = __builtin_amdgcn_mfma_f32_16x16x32_fp8_fp8(a1, bfr[2 * kp + 1], S1, 0, 0, 0);
            }
        }
        const v4f S = S0 + S1;

        // ---- Phase C(it): w = exp2(pre + S*coef); write 64*w fp8 to sW[sp]
        {
            const float4 r4 = *(const float4*)(smem + SRSQ_OFF + it * 128 + nt * 64 + quad * 16);
            float w4[4];
            w4[0] = exp2f(fmaf(S[0], S_COEF, xsqp_lane + r4.x));
            w4[1] = exp2f(fmaf(S[1], S_COEF, xsqp_lane + r4.y));
            w4[2] = exp2f(fmaf(S[2], S_COEF, xsqp_lane + r4.z));
            w4[3] = exp2f(fmaf(S[3], S_COEF, xsqp_lane + r4.w));
            wsum_acc += w4[0] + w4[1] + w4[2] + w4[3];
            const unsigned pk = f2fp8pk4(w4[0] * 64.f, w4[1] * 64.f, w4[2] * 64.f, w4[3] * 64.f);
            const int bl = btA * 16 + l16;
            const int c8 = nt * 2 + (quad >> 1);
            *(unsigned*)(smem + SW_OFF + sp * 2048 + bl * 32
                         + (c8 ^ ((bl >> 2) & 3)) * 8 + (quad & 1) * 4) = pk;
        }

        // ---- Phase D(it-1)
        if (it > 0) {
            const char* swb  = smem + SW_OFF  + spn * 2048;
            const char* stb  = smem + ST_OFF  + tpd * 8192;
            const char* st2b = smem + ST2_OFF + tpd * 8192;
            long wf[4];
#pragma unroll
            for (int bt = 0; bt < 4; ++bt) {
                const int bl = bt * 16 + l16;
                wf[bt] = *(const long*)(swb + bl * 32 + (quad ^ ((bl >> 2) & 3)) * 8);
            }
#pragma unroll
            for (int dt = 0; dt < 2; ++dt) {
                const int d = dq * 32 + dt * 16 + l16;
                const int co = (quad ^ ((d >> 2) & 3)) * 8;
                const long bT  = *(const long*)(stb  + d * 32 + co);
                const long bT2 = *(const long*)(st2b + d * 32 + co);
#pragma unroll
                for (int bt = 0; bt < 4; ++bt) {
                    acc2[bt][dt] = __builtin_amdgcn_mfma_f32_16x16x32_fp8_fp8(wf[bt], bT2, acc2[bt][dt], 0, 0, 0);
                    acc1[bt][dt] = __builtin_amdgcn_mfma_f32_16x16x32_fp8_fp8(wf[bt], bT,  acc1[bt][dt], 0, 0, 0);
                }
            }
        }
        __syncthreads();
        sp = spn; tp = tpn;
    }

    // ---- final Phase D(63)
    {
        const int tpd = (tp == 0) ? 2 : tp - 1;
        const int wsl = sp ^ 1;
        const char* swb  = smem + SW_OFF  + wsl * 2048;
        const char* stb  = smem + ST_OFF  + tpd * 8192;
        const char* st2b = smem + ST2_OFF + tpd * 8192;
        long wf[4];
#pragma unroll
        for (int bt = 0; bt < 4; ++bt) {
            const int bl = bt * 16 + l16;
            wf[bt] = *(const long*)(swb + bl * 32 + (quad ^ ((bl >> 2) & 3)) * 8);
        }
#pragma unroll
        for (int dt = 0; dt < 2; ++dt) {
            const int d = dq * 32 + dt * 16 + l16;
            const int co = (quad ^ ((d >> 2) & 3)) * 8;
            const long bT  = *(const long*)(stb  + d * 32 + co);
            const long bT2 = *(const long*)(st2b + d * 32 + co);
#pragma unroll
            for (int bt = 0; bt < 4; ++bt) {
                acc2[bt][dt] = __builtin_amdgcn_mfma_f32_16x16x32_fp8_fp8(wf[bt], bT2, acc2[bt][dt], 0, 0, 0);
                acc1[bt][dt] = __builtin_amdgcn_mfma_f32_16x16x32_fp8_fp8(wf[bt], bT,  acc1[bt][dt], 0, 0, 0);
            }
        }
    }

    // ---- epilogue: wsum reduce, combine M partial, store
    float v = wsum_acc;
    v += __shfl_xor(v, 16, 64);
    v += __shfl_xor(v, 32, 64);
    float* swsum = (float*)(smem + SWS_OFF);
    if (lane < 16) swsum[wave * 16 + lane] = v;
    __syncthreads();

    float* Mq = ATOMIC ? M : (M + (size_t)q * BB * DD);
    const float inv64 = 0.015625f;
#pragma unroll
    for (int bt = 0; bt < 4; ++bt) {
#pragma unroll
        for (int dt = 0; dt < 2; ++dt) {
            const int d = dq * 32 + dt * 16 + l16;
#pragma unroll
            for (int r = 0; r < 4; ++r) {
                const int bl = bt * 16 + quad * 4 + r;
                const int b = b0 + bl;
                const float wsb = swsum[(bt * 2) * 16 + (quad * 4 + r)]
                                + swsum[(bt * 2 + 1) * 16 + (quad * 4 + r)];
                const float xv = x_t[(size_t)b * DD + d];
                const float m = (acc2[bt][dt][r] - 2.f * xv * acc1[bt][dt][r]) * inv64
                              + xv * xv * wsb;
                if (ATOMIC) atomicAdd(&Mq[(size_t)b * DD + d], m);
                else        Mq[(size_t)b * DD + d] = m;
            }
        }
    }
}

// ---------------- finish (atomic path): out = 1/(W*M + eps) in place
__global__ __launch_bounds__(256) void finish_k(float* __restrict__ M,
                                                const float* __restrict__ W) {
    const int i = blockIdx.x * blockDim.x + threadIdx.x;
    const float W0 = W[0];
    float4 m = ((const float4*)M)[i];
    float4 o;
    o.x = 1.f / (W0 * m.x + EPS_C);
    o.y = 1.f / (W0 * m.y + EPS_C);
    o.z = 1.f / (W0 * m.z + EPS_C);
    o.w = 1.f / (W0 * m.w + EPS_C);
    ((float4*)M)[i] = o;
}

// ---------------- finish (partials path): out = 1/(W*(p0+p1+p2+p3) + eps)
__global__ __launch_bounds__(256) void finish_sum(const float4* __restrict__ Mp,
                                                  const float* __restrict__ W,
                                                  float4* __restrict__ out) {
    const size_t i = (size_t)blockIdx.x * blockDim.x + threadIdx.x;
    const size_t stride = (size_t)BB * DD / 4;
    const float W0 = W[0];
    const float4 a = Mp[i], b = Mp[i + stride], c = Mp[i + 2 * stride], d = Mp[i + 3 * stride];
    float4 o;
    o.x = 1.f / (W0 * (a.x + b.x + c.x + d.x) + EPS_C);
    o.y = 1.f / (W0 * (a.y + b.y + c.y + d.y) + EPS_C);
    o.z = 1.f / (W0 * (a.z + b.z + c.z + d.z) + EPS_C);
    o.w = 1.f / (W0 * (a.w + b.w + c.w + d.w) + EPS_C);
    out[i] = o;
}

// ---------------- fallback: fp32, ZERO workspace (safety net)
__global__ __launch_bounds__(256) void hland_fb(const float* __restrict__ x_t,
                                                const float* __restrict__ ref,
                                                float* __restrict__ M) {
    __shared__ float xs[8][257];
    __shared__ float rt[32][257];
    __shared__ float Sv[8][32];
    __shared__ float wv[8][32];
    __shared__ float rsq_s[32];
    __shared__ float xsq_s[8];
    const int t = threadIdx.x;
    const int b0 = blockIdx.x * 8;
    if (t < 8) xsq_s[t] = 0.f;
    __syncthreads();
    {
        const int r = t >> 5, c = (t & 31) * 8;
        const float4 a = *(const float4*)(x_t + (size_t)(b0 + r) * DD + c);
        const float4 b = *(const float4*)(x_t + (size_t)(b0 + r) * DD + c + 4);
        xs[r][c + 0] = a.x; xs[r][c + 1] = a.y; xs[r][c + 2] = a.z; xs[r][c + 3] = a.w;
        xs[r][c + 4] = b.x; xs[r][c + 5] = b.y; xs[r][c + 6] = b.z; xs[r][c + 7] = b.w;
        atomicAdd(&xsq_s[r], a.x*a.x+a.y*a.y+a.z*a.z+a.w*a.w + b.x*b.x+b.y*b.y+b.z*b.z+b.w*b.w);
    }
    __syncthreads();
    float acc2[8], acc1[8], wsum[8];
#pragma unroll
    for (int b = 0; b < 8; ++b) { acc2[b] = 0.f; acc1[b] = 0.f; wsum[b] = 0.f; }
    const int sr = t >> 3, sg = t & 7;
    for (int tile = 0; tile < NN / 32; ++tile) {
        const int n0 = tile * 32;
        Sv[t >> 5][t & 31] = 0.f;
        if (t < 32) rsq_s[t] = 0.f;
        __syncthreads();
        {
            float p = 0.f;
#pragma unroll
            for (int j = 0; j < 8; ++j) {
                const int c = sg * 32 + j * 4;
                const float4 v = *(const float4*)(ref + (size_t)(n0 + sr) * DD + c);
                rt[sr][c + 0] = v.x; rt[sr][c + 1] = v.y; rt[sr][c + 2] = v.z; rt[sr][c + 3] = v.w;
                p += v.x * v.x + v.y * v.y + v.z * v.z + v.w * v.w;
            }
            atomicAdd(&rsq_s[sr], p);
        }
        __syncthreads();
        {
            float part[8];
#pragma unroll
            for (int b = 0; b < 8; ++b) part[b] = 0.f;
            for (int jj = 0; jj < 32; ++jj) {
                const int c = sg * 32 + ((jj + sg * 4) & 31);
                const float rv = rt[sr][c];
#pragma unroll
                for (int b = 0; b < 8; ++b) part[b] += xs[b][c] * rv;
            }
#pragma unroll
            for (int b = 0; b < 8; ++b) atomicAdd(&Sv[b][sr], part[b]);
        }
        __syncthreads();
        {
            const int b = t >> 5, n = t & 31;
            const float dist = xsq_s[b] + rsq_s[n] - 2.f * Sv[b][n];
            wv[b][n] = __expf(dist * (-GAMMA_INV_2SQ));
        }
        __syncthreads();
        for (int n = 0; n < 32; ++n) {
            const float rv = rt[n][t];
            const float rv2 = rv * rv;
#pragma unroll
            for (int b = 0; b < 8; ++b) {
                const float w = wv[b][n];
                acc1[b] += w * rv; acc2[b] += w * rv2; wsum[b] += w;
            }
        }
        __syncthreads();
    }
#pragma unroll
    for (int b = 0; b < 8; ++b) {
        const float xv = xs[b][t];
        M[(size_t)(b0 + b) * DD + t] = acc2[b] - 2.f * xv * acc1[b] + xv * xv * wsum[b];
    }
}

extern "C" void kernel_launch(void* const* d_in, const int* in_sizes, int n_in,
                              void* d_out, int out_size, void* d_ws, size_t ws_size,
                              hipStream_t stream) {
    const float* x_t = (const float*)d_in[0];
    const float* ref = (const float*)d_in[1];
    const float* W   = (const float*)d_in[2];
    float* out = (float*)d_out;

    const size_t PART_SZ = (size_t)BB * DD * 4;                       // 8 MB per partial
    const size_t TILES_SZ = (size_t)8 * 1024 * 1024 + 96 * 1024;      // images + rsq/xsq
    const size_t WS_A = 4 * PART_SZ + TILES_SZ;                       // ~40.1 MB
    const size_t WS_B = TILES_SZ;                                     // ~8.1 MB

    if (ws_size >= WS_B) {
        const bool partials = (ws_size >= WS_A);
        char* ws = (char*)d_ws;
        float* Mp = (float*)ws;                                       // 4 partials (path A)
        char* tb = partials ? (ws + 4 * PART_SZ) : ws;
        unsigned char* sAg  = (unsigned char*)(tb);
        unsigned char* sTg  = (unsigned char*)(tb + (size_t)2 * 1024 * 1024);
        unsigned char* sT2g = (unsigned char*)(tb + (size_t)4 * 1024 * 1024);
        unsigned char* xbf8 = (unsigned char*)(tb + (size_t)6 * 1024 * 1024);
        float* rsq = (float*)(tb + (size_t)8 * 1024 * 1024);
        float* xsq = (float*)(tb + (size_t)8 * 1024 * 1024 + 32768);

        prep_all<<<512, 256, 0, stream>>>(ref, x_t, sAg, sTg, sT2g, xbf8, rsq, xsq,
                                          out, partials ? 0 : 1);
        if (partials) {
            hland_main<false><<<512, 512, 0, stream>>>(sAg, sTg, sT2g, rsq, xsq, xbf8, x_t, Mp);
            finish_sum<<<(BB * DD / 4) / 256, 256, 0, stream>>>((const float4*)Mp, W, (float4*)out);
        } else {
            hland_main<true><<<512, 512, 0, stream>>>(sAg, sTg, sT2g, rsq, xsq, xbf8, x_t, out);
            finish_k<<<(BB * DD / 4) / 256, 256, 0, stream>>>(out, W);
        }
    } else {
        hland_fb<<<BB / 8, 256, 0, stream>>>(x_t, ref, out);
        finish_k<<<(BB * DD / 4) / 256, 256, 0, stream>>>(out, W);
    }
}